// Round 3
// baseline (250.398 us; speedup 1.0000x reference)
//
#include <hip/hip_runtime.h>
#include <cstdint>
#include <cstddef>

#define N_ENT 40000
#define DDIM  128
#define BSZ   1024
#define NJT   313               // ceil(40000/128)
#define NPART (16 * NJT)        // 5008 written partials
#define NGRID 2560              // 8 XCD slots x 40 tile-groups x 8 member-pairs

#define AS1 __attribute__((address_space(1)))
#define AS3 __attribute__((address_space(3)))

typedef short s16x8 __attribute__((ext_vector_type(8)));
typedef float f32x4 __attribute__((ext_vector_type(4)));

// ws layout (bytes), 256-aligned:
//   0       : partials f32[5008]
//   20480   : tpart    f32[1024]
//   24576   : enorm    f32[40000]
//   184576  : cnorm    f32[2048]
//   192768  : c_bf     u16[2048*128]
//   717056  : ent_bf   u16[40000*128]  -> end 10,957,056 B
#define OFF_PART  0
#define OFF_TPART 20480
#define OFF_ENORM 24576
#define OFF_CNORM 184576
#define OFF_CBF   192768
#define OFF_EBF   717056

#define S_CLAMP 15.9423847f      // -ln(2^-23): clip(pred, eps, 1-eps) bound in fp32
#define U_CLAMP 0.159423847f     // S_CLAMP / 100  (s = 100*u)
#define LP_MAX (-1.1920929e-7f)  // ln(fl32(1-1e-7))

__device__ __forceinline__ unsigned short f2bf(float f) {
  uint32_t u = __float_as_uint(f);
  u += 0x7fffu + ((u >> 16) & 1u);   // round-to-nearest-even
  return (unsigned short)(u >> 16);
}

// Skinny prep, float4 width (16 B/lane): two rows per wave, lanes 0..31 ->
// row base, lanes 32..63 -> row base+1. One load chain per wave, fully
// latency-parallel. (R11 showed fusing the entity half into main's staging
// costs ~25 µs of serialized pre-barrier work — async DMA staging wins.)
//  blocks [0,5000): entity rows -> bf16 + fp32 norm.
//  blocks [5000,5256): c rows = ent[h]+r -> bf16 + norm; positive rows also
//    compute the exact target-pair fixup tpart = log(pred) - A',
//    A' = max(-s, -S_CLAMP) = exactly what main_k adds for that element.
__global__ __launch_bounds__(256) void prep_k(const float* __restrict__ ent,
                                              const int* __restrict__ pos_h,
                                              const int* __restrict__ pos_t,
                                              const int* __restrict__ neg_h,
                                              const float* __restrict__ rpos,
                                              const float* __restrict__ rneg,
                                              const int* __restrict__ l1_flag,
                                              unsigned short* __restrict__ ent_bf,
                                              float* __restrict__ enorm,
                                              unsigned short* __restrict__ c_bf,
                                              float* __restrict__ cnorm,
                                              float* __restrict__ tpart) {
  const int lane = threadIdx.x & 63, wv = threadIdx.x >> 6;
  const int ih = lane >> 5, il = lane & 31;      // half-index, lane-in-half
  const int blk = blockIdx.x;
  if (blk < 5000) {
    int row = blk * 8 + wv * 2 + ih;             // 0..39999
    float4 v = reinterpret_cast<const float4*>(ent + (size_t)row * DDIM)[il];
    ushort4 h4; h4.x = f2bf(v.x); h4.y = f2bf(v.y); h4.z = f2bf(v.z); h4.w = f2bf(v.w);
    reinterpret_cast<ushort4*>(ent_bf + (size_t)row * DDIM)[il] = h4;
    float sq = fmaf(v.x, v.x, fmaf(v.y, v.y, fmaf(v.z, v.z, v.w * v.w)));
    #pragma unroll
    for (int m = 1; m <= 16; m <<= 1) sq += __shfl_xor(sq, m);   // within 32-lane half
    if (il == 0) enorm[row] = sq;
  } else {
    int row = (blk - 5000) * 8 + wv * 2 + ih;    // 0..2047
    int br = row >> 10, i = row & 1023;
    int h = br ? neg_h[i] : pos_h[i];
    const float* rs = br ? rneg : rpos;
    float4 e  = reinterpret_cast<const float4*>(ent + (size_t)h * DDIM)[il];
    float4 rv = reinterpret_cast<const float4*>(rs + (size_t)i * DDIM)[il];
    float c0 = e.x + rv.x, c1 = e.y + rv.y, c2 = e.z + rv.z, c3 = e.w + rv.w;
    ushort4 h4; h4.x = f2bf(c0); h4.y = f2bf(c1); h4.z = f2bf(c2); h4.w = f2bf(c3);
    reinterpret_cast<ushort4*>(c_bf + (size_t)row * DDIM)[il] = h4;
    float sq = fmaf(c0, c0, fmaf(c1, c1, fmaf(c2, c2, c3 * c3)));
    #pragma unroll
    for (int m = 1; m <= 16; m <<= 1) sq += __shfl_xor(sq, m);
    if (il == 0) cnorm[row] = sq;
    if (br == 0) {
      int t = pos_t[i];
      float4 et = reinterpret_cast<const float4*>(ent + (size_t)t * DDIM)[il];
      float d0 = c0 - et.x, d1 = c1 - et.y, d2v = c2 - et.z, d3 = c3 - et.w;
      float d2 = fmaf(d0, d0, fmaf(d1, d1, fmaf(d2v, d2v, d3 * d3)));
      float m1 = fabsf(d0) + fabsf(d1) + fabsf(d2v) + fabsf(d3);
      #pragma unroll
      for (int m = 1; m <= 16; m <<= 1) { d2 += __shfl_xor(d2, m); m1 += __shfl_xor(m1, m); }
      if (il == 0) {
        float s = (*l1_flag) ? (100.f / fmaxf(m1, 1e-12f))
                             : (100.f * rsqrtf(fmaxf(d2, 0.f)));  // d2=0 -> inf, clamps ok
        float x  = __expf(-s);
        float L  = log1pf(x);
        float Bt = fminf(-L, LP_MAX);          // exact log(pred)
        float Ap = fmaxf(-s, -S_CLAMP);        // what main_k adds for this element
        tpart[i] = Bt - Ap;
      }
    }
  }
}

// Main, R13/R14: B-tile reuse at PAIR granularity. R12 post-mortem: 4 members
// per block pushed VGPR 84->140 (past the 128 cliff) -> 2 blocks/CU, occupancy
// 28->10%, main 62.5->80.8 µs. The reuse idea was right; the register cost
// wasn't. Now each block owns (jt, p) and runs the 2 branches of i-tile p from
// ONE staged B tile: blocks 5008->2560 (half of R10's stage/drain overhead).
// Member 1 state is member 0 state + an immediate offset (A rows +1024*DDIM,
// cnorm +1024) -> near-zero extra live registers; __launch_bounds__(256,4)
// pins the 128-VGPR / 4-blocks-per-CU operating point (LDS 4x33KB=132<=160KB).
// Cross-member prefetch: member-1 kc0 frags into the dead av[0] slot + cnorm
// reload under member-0's epilogue. Per-mm math, reduction order and
// partials[jt*16+mm] values stay bit-identical to R10 (mm = p*2+k: branch=k,
// it=p — same decode as mm&1 / mm>>1). XCD swizzle kept: all 8 pairs of a jt
// share id%8 -> one XCD L2 (R10-verified FETCH 41->7 MB).
__global__ __launch_bounds__(256, 4) void main_k(const unsigned short* __restrict__ c_bf,
                                                 const unsigned short* __restrict__ ent_bf,
                                                 const float* __restrict__ cnorm,
                                                 const float* __restrict__ enorm,
                                                 const int* __restrict__ l1_flag,
                                                 const int* __restrict__ pos_h,
                                                 const int* __restrict__ neg_h,
                                                 const float* __restrict__ rpos,
                                                 const float* __restrict__ rneg,
                                                 const float* __restrict__ ent_f32,
                                                 float* __restrict__ partials) {
  __shared__ unsigned short smem[128 * 128];    // 32 KB swizzled B tile
  __shared__ float s4[2][4];                    // [member k][wave]
  const int id = blockIdx.x;
  const int c8 = id & 7;
  const int q  = id >> 3;                        // 0..319
  const int tg = q >> 3;                         // 0..39
  const int p  = q & 7;                          // i-tile 0..7
  const int jt = c8 + tg * 8;                    // 0..319
  if (jt >= NJT) return;                         // block-uniform, pre-barrier
  const int j0 = jt * 128, i0 = p * 128;
  const int tid = threadIdx.x, lane = tid & 63, wv = tid >> 6;
  const int wm = wv >> 1, wn = wv & 1;
  const int r15 = lane & 15, quad = lane >> 4;

  // ---- async stage B tile: 2048 x 16B chunks, swizzled c' = c ^ (row&15) ----
  #pragma unroll
  for (int i = 0; i < 8; ++i) {
    int g  = i * 256 + tid;        // LDS dst = uniform base + lane*16 (m104 rule)
    int r  = g >> 4;
    int cp = g & 15;
    int c  = cp ^ (r & 15);
    int jr = j0 + r; if (jr >= N_ENT) jr = N_ENT - 1;   // clamp; masked in epilogue
    const unsigned short* src = ent_bf + (size_t)jr * DDIM + c * 8;
    __builtin_amdgcn_global_load_lds((const AS1 void*)src, (AS3 void*)(&smem[g * 8]), 16, 0, 0);
  }

  // member-1 offsets: branch bit adds 1024 rows in c_bf / cnorm
  #define AOFF ((size_t)1024 * DDIM)

  // ---- member-0 A pointers + kc0 prefetch + norms (land under stage drain) ----
  const unsigned short* arow[4];
  #pragma unroll
  for (int tm = 0; tm < 4; ++tm)
    arow[tm] = c_bf + (size_t)(i0 + wm * 64 + tm * 16 + r15) * DDIM + quad * 8;

  s16x8 av[2][4];
  #pragma unroll
  for (int tm = 0; tm < 4; ++tm)
    av[0][tm] = *reinterpret_cast<const s16x8*>(arow[tm]);

  float cnvA[16];
  #pragma unroll
  for (int tm = 0; tm < 4; ++tm)
    #pragma unroll
    for (int r = 0; r < 4; ++r)
      cnvA[tm * 4 + r] = cnorm[i0 + wm * 64 + tm * 16 + quad * 4 + r];

  float en[4];
  #pragma unroll
  for (int tn = 0; tn < 4; ++tn) {
    int jg = j0 + wn * 64 + tn * 16 + r15;
    en[tn] = enorm[jg < N_ENT ? jg : N_ENT - 1];
  }

  const int l1 = *l1_flag;
  const bool full = (j0 + 128) <= N_ENT;   // block-uniform
  const f32x4 zf = {0.f, 0.f, 0.f, 0.f};

  __syncthreads();   // drains vmcnt: B tile staged (A kc0 + norms also landed)

  #pragma unroll 1
  for (int k = 0; k < 2; ++k) {
    const size_t ab = k ? AOFF : 0;        // branch offset for this member

    f32x4 acc[4][4];
    #pragma unroll
    for (int a = 0; a < 4; ++a)
      #pragma unroll
      for (int b = 0; b < 4; ++b) acc[a][b] = zf;

    #pragma unroll
    for (int kc = 0; kc < 4; ++kc) {
      if (kc < 3) {
        #pragma unroll
        for (int tm = 0; tm < 4; ++tm)
          av[(kc + 1) & 1][tm] = *reinterpret_cast<const s16x8*>(arow[tm] + ab + (kc + 1) * 32);
      }
      s16x8 bv[4];
      #pragma unroll
      for (int tn = 0; tn < 4; ++tn) {
        int R  = wn * 64 + tn * 16 + r15;
        int cs = (kc * 4 + quad) ^ r15;
        bv[tn] = *reinterpret_cast<const s16x8*>(&smem[R * 128 + cs * 8]);
      }
      #pragma unroll
      for (int tm = 0; tm < 4; ++tm)
        #pragma unroll
        for (int tn = 0; tn < 4; ++tn)
          acc[tm][tn] = __builtin_amdgcn_mfma_f32_16x16x32_bf16(av[kc & 1][tm], bv[tn], acc[tm][tn], 0, 0, 0);
    }

    // Prefetch member-1 kc0 frags into the dead av[0] slot; lands under epilogue.
    if (k == 0) {
      #pragma unroll
      for (int tm = 0; tm < 4; ++tm)
        av[0][tm] = *reinterpret_cast<const s16x8*>(arow[tm] + AOFF);
    }

    // ---- 5-inst epilogue: add, fma, rsqrt, fmin, add (u-units), 4 accumulators ----
    float ls0 = 0.f, ls1 = 0.f, ls2 = 0.f, ls3 = 0.f;
    if (!l1) {
      #pragma unroll
      for (int tm = 0; tm < 4; ++tm) {
        if (full) {
          #pragma unroll
          for (int tn = 0; tn < 4; ++tn) {
            float e0 = en[tn];
            float u0 = rsqrtf(fmaf(-2.f, acc[tm][tn][0], cnvA[tm * 4 + 0] + e0));
            float u1 = rsqrtf(fmaf(-2.f, acc[tm][tn][1], cnvA[tm * 4 + 1] + e0));
            float u2 = rsqrtf(fmaf(-2.f, acc[tm][tn][2], cnvA[tm * 4 + 2] + e0));
            float u3 = rsqrtf(fmaf(-2.f, acc[tm][tn][3], cnvA[tm * 4 + 3] + e0));
            ls0 += fminf(u0, U_CLAMP);         // <=0/NaN -> fmin clamps
            ls1 += fminf(u1, U_CLAMP);
            ls2 += fminf(u2, U_CLAMP);
            ls3 += fminf(u3, U_CLAMP);
          }
        } else {
          #pragma unroll
          for (int tn = 0; tn < 4; ++tn) {
            int jg = j0 + wn * 64 + tn * 16 + r15;
            if (jg < N_ENT) {
              float e0 = en[tn];
              ls0 += fminf(rsqrtf(fmaf(-2.f, acc[tm][tn][0], cnvA[tm * 4 + 0] + e0)), U_CLAMP);
              ls1 += fminf(rsqrtf(fmaf(-2.f, acc[tm][tn][1], cnvA[tm * 4 + 1] + e0)), U_CLAMP);
              ls2 += fminf(rsqrtf(fmaf(-2.f, acc[tm][tn][2], cnvA[tm * 4 + 2] + e0)), U_CLAMP);
              ls3 += fminf(rsqrtf(fmaf(-2.f, acc[tm][tn][3], cnvA[tm * 4 + 3] + e0)), U_CLAMP);
            }
          }
        }
      }
    } else {
      // L1 fallback (dead with this harness's inputs): recompute on the fly.
      const float* rs = k ? rneg : rpos;
      const int*   hb = k ? neg_h : pos_h;
      #pragma unroll 1
      for (int tm = 0; tm < 4; ++tm) {
        #pragma unroll 1
        for (int r = 0; r < 4; ++r) {
          int bi = i0 + wm * 64 + tm * 16 + quad * 4 + r;
          int hh = hb[bi];
          #pragma unroll 1
          for (int tn = 0; tn < 4; ++tn) {
            int jg = j0 + wn * 64 + tn * 16 + r15;
            if (jg < N_ENT) {
              const float* cp1 = ent_f32 + (size_t)hh * DDIM;
              const float* cp2 = rs + (size_t)bi * DDIM;
              const float* ep  = ent_f32 + (size_t)jg * DDIM;
              float man = 0.f;
              #pragma unroll 1
              for (int d = 0; d < DDIM; ++d) man += fabsf(cp1[d] + cp2[d] - ep[d]);
              float s = 100.f / fmaxf(man, 1e-12f);
              ls0 += 0.01f * fminf(s, S_CLAMP);   // same u-unit scale
            }
          }
        }
      }
    }
    float lsum = (ls0 + ls1) + (ls2 + ls3);

    #pragma unroll
    for (int m = 32; m; m >>= 1) lsum += __shfl_xor(lsum, m);
    if (lane == 0) s4[k][wv] = lsum;

    // Reload cnorm for member 1 AFTER its last use; consumed only in the
    // next epilogue (in flight across the loop edge, fully hidden).
    if (k == 0) {
      #pragma unroll
      for (int tm = 0; tm < 4; ++tm)
        #pragma unroll
        for (int r = 0; r < 4; ++r)
          cnvA[tm * 4 + r] = cnorm[1024 + i0 + wm * 64 + tm * 16 + quad * 4 + r];
    }
  }

  __syncthreads();
  if (tid < 2)
    partials[jt * 16 + p * 2 + tid] = s4[tid][0] + s4[tid][1] + s4[tid][2] + s4[tid][3];
  #undef AOFF
}

// Single-block deterministic finalize: 1024 threads; each sums ~5 partials
// (x 100/(B*N)) + its tpart element (x -1/(B*N)) in double, block-reduce,
// one plain store. No atomics -> no d_out memset node needed.
__global__ __launch_bounds__(1024) void finalize_k(const float* __restrict__ partials,
                                                   const float* __restrict__ tpart,
                                                   float* __restrict__ out) {
  const int tid = threadIdx.x, lane = tid & 63, wv = tid >> 6;
  const double inv = 1.0 / ((double)BSZ * (double)N_ENT);
  double v = 0.0;
  for (int i = tid; i < NPART; i += 1024) v += (double)partials[i] * (100.0 * inv);
  v += (double)tpart[tid] * (-inv);
  #pragma unroll
  for (int m = 32; m; m >>= 1) v += __shfl_xor(v, m);
  __shared__ double sd[16];
  if (lane == 0) sd[wv] = v;
  __syncthreads();
  if (wv == 0) {
    double t = (lane < 16) ? sd[lane] : 0.0;
    #pragma unroll
    for (int m = 8; m; m >>= 1) t += __shfl_xor(t, m);
    if (lane == 0) out[0] = (float)t;
  }
}

extern "C" void kernel_launch(void* const* d_in, const int* in_sizes, int n_in,
                              void* d_out, int out_size, void* d_ws, size_t ws_size,
                              hipStream_t stream) {
  const int*   pos_h = (const int*)d_in[0];
  const int*   pos_t = (const int*)d_in[1];
  const int*   neg_h = (const int*)d_in[2];
  // d_in[3] = neg_t_batch (unused by reference)
  const float* rpos  = (const float*)d_in[4];
  const float* rneg  = (const float*)d_in[5];
  const float* ent   = (const float*)d_in[6];
  const int*   l1    = (const int*)d_in[7];

  char* ws = (char*)d_ws;
  float*          partials = (float*)(ws + OFF_PART);
  float*          tpart    = (float*)(ws + OFF_TPART);
  float*          enorm    = (float*)(ws + OFF_ENORM);
  float*          cnorm    = (float*)(ws + OFF_CNORM);
  unsigned short* c_bf     = (unsigned short*)(ws + OFF_CBF);
  unsigned short* ent_bf   = (unsigned short*)(ws + OFF_EBF);

  prep_k<<<5256, 256, 0, stream>>>(ent, pos_h, pos_t, neg_h, rpos, rneg, l1,
                                   ent_bf, enorm, c_bf, cnorm, tpart);

  main_k<<<NGRID, 256, 0, stream>>>(c_bf, ent_bf, cnorm, enorm, l1,
                                    pos_h, neg_h, rpos, rneg, ent, partials);

  finalize_k<<<1, 1024, 0, stream>>>(partials, tpart, (float*)d_out);
}

// Round 4
// 144.338 us; speedup vs baseline: 1.7348x; 1.7348x over previous
//
#include <hip/hip_runtime.h>
#include <cstdint>
#include <cstddef>

#define N_ENT 40000
#define DDIM  128
#define BSZ   1024
#define NJT   313               // ceil(40000/128)
#define NPART (16 * NJT)        // 5008 written partials
#define NGRID 2560              // 8 XCD slots x 40 tile-groups x 8 member-pairs

#define AS1 __attribute__((address_space(1)))
#define AS3 __attribute__((address_space(3)))

typedef short s16x8 __attribute__((ext_vector_type(8)));
typedef float f32x4 __attribute__((ext_vector_type(4)));

// ws layout (bytes), 256-aligned:
//   0       : partials f32[5008]
//   20480   : tpart    f32[1024]
//   24576   : enorm    f32[40000]
//   184576  : cnorm    f32[2048]
//   192768  : c_bf     u16[2048*128]
//   717056  : ent_bf   u16[40000*128]  -> end 10,957,056 B
#define OFF_PART  0
#define OFF_TPART 20480
#define OFF_ENORM 24576
#define OFF_CNORM 184576
#define OFF_CBF   192768
#define OFF_EBF   717056

#define S_CLAMP 15.9423847f      // -ln(2^-23): clip(pred, eps, 1-eps) bound in fp32
#define U_CLAMP 0.159423847f     // S_CLAMP / 100  (s = 100*u)
#define LP_MAX (-1.1920929e-7f)  // ln(fl32(1-1e-7))

__device__ __forceinline__ unsigned short f2bf(float f) {
  uint32_t u = __float_as_uint(f);
  u += 0x7fffu + ((u >> 16) & 1u);   // round-to-nearest-even
  return (unsigned short)(u >> 16);
}

// Skinny prep, float4 width (16 B/lane): two rows per wave, lanes 0..31 ->
// row base, lanes 32..63 -> row base+1. One load chain per wave, fully
// latency-parallel. (R11 showed fusing the entity half into main's staging
// costs ~25 µs of serialized pre-barrier work — async DMA staging wins.)
//  blocks [0,5000): entity rows -> bf16 + fp32 norm.
//  blocks [5000,5256): c rows = ent[h]+r -> bf16 + norm; positive rows also
//    compute the exact target-pair fixup tpart = log(pred) - A',
//    A' = max(-s, -S_CLAMP) = exactly what main_k adds for that element.
__global__ __launch_bounds__(256) void prep_k(const float* __restrict__ ent,
                                              const int* __restrict__ pos_h,
                                              const int* __restrict__ pos_t,
                                              const int* __restrict__ neg_h,
                                              const float* __restrict__ rpos,
                                              const float* __restrict__ rneg,
                                              const int* __restrict__ l1_flag,
                                              unsigned short* __restrict__ ent_bf,
                                              float* __restrict__ enorm,
                                              unsigned short* __restrict__ c_bf,
                                              float* __restrict__ cnorm,
                                              float* __restrict__ tpart) {
  const int lane = threadIdx.x & 63, wv = threadIdx.x >> 6;
  const int ih = lane >> 5, il = lane & 31;      // half-index, lane-in-half
  const int blk = blockIdx.x;
  if (blk < 5000) {
    int row = blk * 8 + wv * 2 + ih;             // 0..39999
    float4 v = reinterpret_cast<const float4*>(ent + (size_t)row * DDIM)[il];
    ushort4 h4; h4.x = f2bf(v.x); h4.y = f2bf(v.y); h4.z = f2bf(v.z); h4.w = f2bf(v.w);
    reinterpret_cast<ushort4*>(ent_bf + (size_t)row * DDIM)[il] = h4;
    float sq = fmaf(v.x, v.x, fmaf(v.y, v.y, fmaf(v.z, v.z, v.w * v.w)));
    #pragma unroll
    for (int m = 1; m <= 16; m <<= 1) sq += __shfl_xor(sq, m);   // within 32-lane half
    if (il == 0) enorm[row] = sq;
  } else {
    int row = (blk - 5000) * 8 + wv * 2 + ih;    // 0..2047
    int br = row >> 10, i = row & 1023;
    int h = br ? neg_h[i] : pos_h[i];
    const float* rs = br ? rneg : rpos;
    float4 e  = reinterpret_cast<const float4*>(ent + (size_t)h * DDIM)[il];
    float4 rv = reinterpret_cast<const float4*>(rs + (size_t)i * DDIM)[il];
    float c0 = e.x + rv.x, c1 = e.y + rv.y, c2 = e.z + rv.z, c3 = e.w + rv.w;
    ushort4 h4; h4.x = f2bf(c0); h4.y = f2bf(c1); h4.z = f2bf(c2); h4.w = f2bf(c3);
    reinterpret_cast<ushort4*>(c_bf + (size_t)row * DDIM)[il] = h4;
    float sq = fmaf(c0, c0, fmaf(c1, c1, fmaf(c2, c2, c3 * c3)));
    #pragma unroll
    for (int m = 1; m <= 16; m <<= 1) sq += __shfl_xor(sq, m);
    if (il == 0) cnorm[row] = sq;
    if (br == 0) {
      int t = pos_t[i];
      float4 et = reinterpret_cast<const float4*>(ent + (size_t)t * DDIM)[il];
      float d0 = c0 - et.x, d1 = c1 - et.y, d2v = c2 - et.z, d3 = c3 - et.w;
      float d2 = fmaf(d0, d0, fmaf(d1, d1, fmaf(d2v, d2v, d3 * d3)));
      float m1 = fabsf(d0) + fabsf(d1) + fabsf(d2v) + fabsf(d3);
      #pragma unroll
      for (int m = 1; m <= 16; m <<= 1) { d2 += __shfl_xor(d2, m); m1 += __shfl_xor(m1, m); }
      if (il == 0) {
        float s = (*l1_flag) ? (100.f / fmaxf(m1, 1e-12f))
                             : (100.f * rsqrtf(fmaxf(d2, 0.f)));  // d2=0 -> inf, clamps ok
        float x  = __expf(-s);
        float L  = log1pf(x);
        float Bt = fminf(-L, LP_MAX);          // exact log(pred)
        float Ap = fmaxf(-s, -S_CLAMP);        // what main_k adds for this element
        tpart[i] = Bt - Ap;
      }
    }
  }
}

// Main, R15: pair-granularity B-tile reuse, NATURAL register allocation.
// R13/R14 post-mortem: __launch_bounds__(256,4) forced a ~128-reg unified
// VGPR+AGPR budget; acc[4][4] (64 AGPRs) ate half -> VGPR_Count 64 + massive
// scratch spills (FETCH 300MB / WRITE 430MB of spill traffic = the whole
// 176 µs). Lesson: occupancy bounds must budget the accumulator tile on
// gfx950's unified file. Fix: plain __launch_bounds__(256) (R10's 84-VGPR
// regime) + FULLY UNROLLED k-loop so the member index, the +1024*DDIM branch
// offset, and the prefetch guards constant-fold — no live runtime offsets.
// Each block owns (jt,p), runs branch 0 then branch 1 of i-tile p off ONE
// staged B tile: 2560 blocks vs R10's 5008 -> half the stage/drain events.
// Per-mm math, reduction order and partials[jt*16+mm] stay bit-identical to
// R10 (mm = p*2+k). XCD swizzle kept: all pairs of a jt share id%8 -> one
// XCD L2 (R10-verified FETCH 41->7 MB).
__global__ __launch_bounds__(256) void main_k(const unsigned short* __restrict__ c_bf,
                                              const unsigned short* __restrict__ ent_bf,
                                              const float* __restrict__ cnorm,
                                              const float* __restrict__ enorm,
                                              const int* __restrict__ l1_flag,
                                              const int* __restrict__ pos_h,
                                              const int* __restrict__ neg_h,
                                              const float* __restrict__ rpos,
                                              const float* __restrict__ rneg,
                                              const float* __restrict__ ent_f32,
                                              float* __restrict__ partials) {
  __shared__ unsigned short smem[128 * 128];    // 32 KB swizzled B tile
  __shared__ float s4[2][4];                    // [member k][wave]
  const int id = blockIdx.x;
  const int c8 = id & 7;
  const int q  = id >> 3;                        // 0..319
  const int tg = q >> 3;                         // 0..39
  const int p  = q & 7;                          // i-tile 0..7
  const int jt = c8 + tg * 8;                    // 0..319
  if (jt >= NJT) return;                         // block-uniform, pre-barrier
  const int j0 = jt * 128, i0 = p * 128;
  const int tid = threadIdx.x, lane = tid & 63, wv = tid >> 6;
  const int wm = wv >> 1, wn = wv & 1;
  const int r15 = lane & 15, quad = lane >> 4;

  // ---- async stage B tile: 2048 x 16B chunks, swizzled c' = c ^ (row&15) ----
  #pragma unroll
  for (int i = 0; i < 8; ++i) {
    int g  = i * 256 + tid;        // LDS dst = uniform base + lane*16 (m104 rule)
    int r  = g >> 4;
    int cp = g & 15;
    int c  = cp ^ (r & 15);
    int jr = j0 + r; if (jr >= N_ENT) jr = N_ENT - 1;   // clamp; masked in epilogue
    const unsigned short* src = ent_bf + (size_t)jr * DDIM + c * 8;
    __builtin_amdgcn_global_load_lds((const AS1 void*)src, (AS3 void*)(&smem[g * 8]), 16, 0, 0);
  }

  // member-1 offsets: branch bit adds 1024 rows in c_bf / cnorm
  #define AOFF ((size_t)1024 * DDIM)

  // ---- member-0 A pointers + kc0 prefetch + norms (land under stage drain) ----
  const unsigned short* arow[4];
  #pragma unroll
  for (int tm = 0; tm < 4; ++tm)
    arow[tm] = c_bf + (size_t)(i0 + wm * 64 + tm * 16 + r15) * DDIM + quad * 8;

  s16x8 av[2][4];
  #pragma unroll
  for (int tm = 0; tm < 4; ++tm)
    av[0][tm] = *reinterpret_cast<const s16x8*>(arow[tm]);

  float cnvA[16];
  #pragma unroll
  for (int tm = 0; tm < 4; ++tm)
    #pragma unroll
    for (int r = 0; r < 4; ++r)
      cnvA[tm * 4 + r] = cnorm[i0 + wm * 64 + tm * 16 + quad * 4 + r];

  float en[4];
  #pragma unroll
  for (int tn = 0; tn < 4; ++tn) {
    int jg = j0 + wn * 64 + tn * 16 + r15;
    en[tn] = enorm[jg < N_ENT ? jg : N_ENT - 1];
  }

  const int l1 = *l1_flag;
  const bool full = (j0 + 128) <= N_ENT;   // block-uniform
  const f32x4 zf = {0.f, 0.f, 0.f, 0.f};

  __syncthreads();   // drains vmcnt: B tile staged (A kc0 + norms also landed)

  #pragma unroll   // FULL unroll: k, branch offset, prefetch guards constant-fold
  for (int k = 0; k < 2; ++k) {
    f32x4 acc[4][4];
    #pragma unroll
    for (int a = 0; a < 4; ++a)
      #pragma unroll
      for (int b = 0; b < 4; ++b) acc[a][b] = zf;

    #pragma unroll
    for (int kc = 0; kc < 4; ++kc) {
      if (kc < 3) {
        #pragma unroll
        for (int tm = 0; tm < 4; ++tm)
          av[(kc + 1) & 1][tm] = *reinterpret_cast<const s16x8*>(
              arow[tm] + (k ? AOFF : 0) + (kc + 1) * 32);
      }
      s16x8 bv[4];
      #pragma unroll
      for (int tn = 0; tn < 4; ++tn) {
        int R  = wn * 64 + tn * 16 + r15;
        int cs = (kc * 4 + quad) ^ r15;
        bv[tn] = *reinterpret_cast<const s16x8*>(&smem[R * 128 + cs * 8]);
      }
      #pragma unroll
      for (int tm = 0; tm < 4; ++tm)
        #pragma unroll
        for (int tn = 0; tn < 4; ++tn)
          acc[tm][tn] = __builtin_amdgcn_mfma_f32_16x16x32_bf16(av[kc & 1][tm], bv[tn], acc[tm][tn], 0, 0, 0);
    }

    // Prefetch member-1 kc0 frags into the dead av[0] slot; lands under epilogue.
    if (k == 0) {
      #pragma unroll
      for (int tm = 0; tm < 4; ++tm)
        av[0][tm] = *reinterpret_cast<const s16x8*>(arow[tm] + AOFF);
    }

    // ---- 5-inst epilogue: add, fma, rsqrt, fmin, add (u-units), 4 accumulators ----
    float ls0 = 0.f, ls1 = 0.f, ls2 = 0.f, ls3 = 0.f;
    if (!l1) {
      #pragma unroll
      for (int tm = 0; tm < 4; ++tm) {
        if (full) {
          #pragma unroll
          for (int tn = 0; tn < 4; ++tn) {
            float e0 = en[tn];
            float u0 = rsqrtf(fmaf(-2.f, acc[tm][tn][0], cnvA[tm * 4 + 0] + e0));
            float u1 = rsqrtf(fmaf(-2.f, acc[tm][tn][1], cnvA[tm * 4 + 1] + e0));
            float u2 = rsqrtf(fmaf(-2.f, acc[tm][tn][2], cnvA[tm * 4 + 2] + e0));
            float u3 = rsqrtf(fmaf(-2.f, acc[tm][tn][3], cnvA[tm * 4 + 3] + e0));
            ls0 += fminf(u0, U_CLAMP);         // <=0/NaN -> fmin clamps
            ls1 += fminf(u1, U_CLAMP);
            ls2 += fminf(u2, U_CLAMP);
            ls3 += fminf(u3, U_CLAMP);
          }
        } else {
          #pragma unroll
          for (int tn = 0; tn < 4; ++tn) {
            int jg = j0 + wn * 64 + tn * 16 + r15;
            if (jg < N_ENT) {
              float e0 = en[tn];
              ls0 += fminf(rsqrtf(fmaf(-2.f, acc[tm][tn][0], cnvA[tm * 4 + 0] + e0)), U_CLAMP);
              ls1 += fminf(rsqrtf(fmaf(-2.f, acc[tm][tn][1], cnvA[tm * 4 + 1] + e0)), U_CLAMP);
              ls2 += fminf(rsqrtf(fmaf(-2.f, acc[tm][tn][2], cnvA[tm * 4 + 2] + e0)), U_CLAMP);
              ls3 += fminf(rsqrtf(fmaf(-2.f, acc[tm][tn][3], cnvA[tm * 4 + 3] + e0)), U_CLAMP);
            }
          }
        }
      }
    } else {
      // L1 fallback (dead with this harness's inputs): recompute on the fly.
      const float* rs = k ? rneg : rpos;
      const int*   hb = k ? neg_h : pos_h;
      #pragma unroll 1
      for (int tm = 0; tm < 4; ++tm) {
        #pragma unroll 1
        for (int r = 0; r < 4; ++r) {
          int bi = i0 + wm * 64 + tm * 16 + quad * 4 + r;
          int hh = hb[bi];
          #pragma unroll 1
          for (int tn = 0; tn < 4; ++tn) {
            int jg = j0 + wn * 64 + tn * 16 + r15;
            if (jg < N_ENT) {
              const float* cp1 = ent_f32 + (size_t)hh * DDIM;
              const float* cp2 = rs + (size_t)bi * DDIM;
              const float* ep  = ent_f32 + (size_t)jg * DDIM;
              float man = 0.f;
              #pragma unroll 1
              for (int d = 0; d < DDIM; ++d) man += fabsf(cp1[d] + cp2[d] - ep[d]);
              float s = 100.f / fmaxf(man, 1e-12f);
              ls0 += 0.01f * fminf(s, S_CLAMP);   // same u-unit scale
            }
          }
        }
      }
    }
    float lsum = (ls0 + ls1) + (ls2 + ls3);

    #pragma unroll
    for (int m = 32; m; m >>= 1) lsum += __shfl_xor(lsum, m);
    if (lane == 0) s4[k][wv] = lsum;

    // Reload cnorm for member 1 AFTER its last use; consumed only in the
    // next epilogue (in flight across the loop edge, fully hidden).
    if (k == 0) {
      #pragma unroll
      for (int tm = 0; tm < 4; ++tm)
        #pragma unroll
        for (int r = 0; r < 4; ++r)
          cnvA[tm * 4 + r] = cnorm[1024 + i0 + wm * 64 + tm * 16 + quad * 4 + r];
    }
  }

  __syncthreads();
  if (tid < 2)
    partials[jt * 16 + p * 2 + tid] = s4[tid][0] + s4[tid][1] + s4[tid][2] + s4[tid][3];
  #undef AOFF
}

// Single-block deterministic finalize: 1024 threads; each sums ~5 partials
// (x 100/(B*N)) + its tpart element (x -1/(B*N)) in double, block-reduce,
// one plain store. No atomics -> no d_out memset node needed.
__global__ __launch_bounds__(1024) void finalize_k(const float* __restrict__ partials,
                                                   const float* __restrict__ tpart,
                                                   float* __restrict__ out) {
  const int tid = threadIdx.x, lane = tid & 63, wv = tid >> 6;
  const double inv = 1.0 / ((double)BSZ * (double)N_ENT);
  double v = 0.0;
  for (int i = tid; i < NPART; i += 1024) v += (double)partials[i] * (100.0 * inv);
  v += (double)tpart[tid] * (-inv);
  #pragma unroll
  for (int m = 32; m; m >>= 1) v += __shfl_xor(v, m);
  __shared__ double sd[16];
  if (lane == 0) sd[wv] = v;
  __syncthreads();
  if (wv == 0) {
    double t = (lane < 16) ? sd[lane] : 0.0;
    #pragma unroll
    for (int m = 8; m; m >>= 1) t += __shfl_xor(t, m);
    if (lane == 0) out[0] = (float)t;
  }
}

extern "C" void kernel_launch(void* const* d_in, const int* in_sizes, int n_in,
                              void* d_out, int out_size, void* d_ws, size_t ws_size,
                              hipStream_t stream) {
  const int*   pos_h = (const int*)d_in[0];
  const int*   pos_t = (const int*)d_in[1];
  const int*   neg_h = (const int*)d_in[2];
  // d_in[3] = neg_t_batch (unused by reference)
  const float* rpos  = (const float*)d_in[4];
  const float* rneg  = (const float*)d_in[5];
  const float* ent   = (const float*)d_in[6];
  const int*   l1    = (const int*)d_in[7];

  char* ws = (char*)d_ws;
  float*          partials = (float*)(ws + OFF_PART);
  float*          tpart    = (float*)(ws + OFF_TPART);
  float*          enorm    = (float*)(ws + OFF_ENORM);
  float*          cnorm    = (float*)(ws + OFF_CNORM);
  unsigned short* c_bf     = (unsigned short*)(ws + OFF_CBF);
  unsigned short* ent_bf   = (unsigned short*)(ws + OFF_EBF);

  prep_k<<<5256, 256, 0, stream>>>(ent, pos_h, pos_t, neg_h, rpos, rneg, l1,
                                   ent_bf, enorm, c_bf, cnorm, tpart);

  main_k<<<NGRID, 256, 0, stream>>>(c_bf, ent_bf, cnorm, enorm, l1,
                                    pos_h, neg_h, rpos, rneg, ent, partials);

  finalize_k<<<1, 1024, 0, stream>>>(partials, tpart, (float*)d_out);
}

// Round 5
// 133.846 us; speedup vs baseline: 1.8708x; 1.0784x over previous
//
#include <hip/hip_runtime.h>
#include <cstdint>
#include <cstddef>

#define N_ENT 40000
#define DDIM  128
#define BSZ   1024
#define NJT   313               // ceil(40000/128)
#define NPART (16 * NJT)        // 5008 written partials
#define CH    5                 // j-tiles per block chunk
#define NGRID 1024              // 64 groups x 16 members (group 63 idle)

#define AS1 __attribute__((address_space(1)))
#define AS3 __attribute__((address_space(3)))

typedef short s16x8 __attribute__((ext_vector_type(8)));
typedef float f32x4 __attribute__((ext_vector_type(4)));

// ws layout (bytes), 256-aligned:
//   0       : partials f32[5008]
//   20480   : tpart    f32[1024]
//   24576   : enorm    f32[40000]
//   184576  : cnorm    f32[2048]
//   192768  : c_bf     u16[2048*128]
//   717056  : ent_bf   u16[40000*128]  -> end 10,957,056 B
#define OFF_PART  0
#define OFF_TPART 20480
#define OFF_ENORM 24576
#define OFF_CNORM 184576
#define OFF_CBF   192768
#define OFF_EBF   717056

#define S_CLAMP 15.9423847f      // -ln(2^-23): clip(pred, eps, 1-eps) bound in fp32
#define U_CLAMP 0.159423847f     // S_CLAMP / 100  (s = 100*u)
#define LP_MAX (-1.1920929e-7f)  // ln(fl32(1-1e-7))

__device__ __forceinline__ unsigned short f2bf(float f) {
  uint32_t u = __float_as_uint(f);
  u += 0x7fffu + ((u >> 16) & 1u);   // round-to-nearest-even
  return (unsigned short)(u >> 16);
}

// Skinny prep, float4 width (16 B/lane): unchanged from R15 (verified).
__global__ __launch_bounds__(256) void prep_k(const float* __restrict__ ent,
                                              const int* __restrict__ pos_h,
                                              const int* __restrict__ pos_t,
                                              const int* __restrict__ neg_h,
                                              const float* __restrict__ rpos,
                                              const float* __restrict__ rneg,
                                              const int* __restrict__ l1_flag,
                                              unsigned short* __restrict__ ent_bf,
                                              float* __restrict__ enorm,
                                              unsigned short* __restrict__ c_bf,
                                              float* __restrict__ cnorm,
                                              float* __restrict__ tpart) {
  const int lane = threadIdx.x & 63, wv = threadIdx.x >> 6;
  const int ih = lane >> 5, il = lane & 31;      // half-index, lane-in-half
  const int blk = blockIdx.x;
  if (blk < 5000) {
    int row = blk * 8 + wv * 2 + ih;             // 0..39999
    float4 v = reinterpret_cast<const float4*>(ent + (size_t)row * DDIM)[il];
    ushort4 h4; h4.x = f2bf(v.x); h4.y = f2bf(v.y); h4.z = f2bf(v.z); h4.w = f2bf(v.w);
    reinterpret_cast<ushort4*>(ent_bf + (size_t)row * DDIM)[il] = h4;
    float sq = fmaf(v.x, v.x, fmaf(v.y, v.y, fmaf(v.z, v.z, v.w * v.w)));
    #pragma unroll
    for (int m = 1; m <= 16; m <<= 1) sq += __shfl_xor(sq, m);   // within 32-lane half
    if (il == 0) enorm[row] = sq;
  } else {
    int row = (blk - 5000) * 8 + wv * 2 + ih;    // 0..2047
    int br = row >> 10, i = row & 1023;
    int h = br ? neg_h[i] : pos_h[i];
    const float* rs = br ? rneg : rpos;
    float4 e  = reinterpret_cast<const float4*>(ent + (size_t)h * DDIM)[il];
    float4 rv = reinterpret_cast<const float4*>(rs + (size_t)i * DDIM)[il];
    float c0 = e.x + rv.x, c1 = e.y + rv.y, c2 = e.z + rv.z, c3 = e.w + rv.w;
    ushort4 h4; h4.x = f2bf(c0); h4.y = f2bf(c1); h4.z = f2bf(c2); h4.w = f2bf(c3);
    reinterpret_cast<ushort4*>(c_bf + (size_t)row * DDIM)[il] = h4;
    float sq = fmaf(c0, c0, fmaf(c1, c1, fmaf(c2, c2, c3 * c3)));
    #pragma unroll
    for (int m = 1; m <= 16; m <<= 1) sq += __shfl_xor(sq, m);
    if (il == 0) cnorm[row] = sq;
    if (br == 0) {
      int t = pos_t[i];
      float4 et = reinterpret_cast<const float4*>(ent + (size_t)t * DDIM)[il];
      float d0 = c0 - et.x, d1 = c1 - et.y, d2v = c2 - et.z, d3 = c3 - et.w;
      float d2 = fmaf(d0, d0, fmaf(d1, d1, fmaf(d2v, d2v, d3 * d3)));
      float m1 = fabsf(d0) + fabsf(d1) + fabsf(d2v) + fabsf(d3);
      #pragma unroll
      for (int m = 1; m <= 16; m <<= 1) { d2 += __shfl_xor(d2, m); m1 += __shfl_xor(m1, m); }
      if (il == 0) {
        float s = (*l1_flag) ? (100.f / fmaxf(m1, 1e-12f))
                             : (100.f * rsqrtf(fmaxf(d2, 0.f)));  // d2=0 -> inf, clamps ok
        float x  = __expf(-s);
        float L  = log1pf(x);
        float Bt = fminf(-L, LP_MAX);          // exact log(pred)
        float Ap = fmaxf(-s, -S_CLAMP);        // what main_k adds for this element
        tpart[i] = Bt - Ap;
      }
    }
  }
}

// Main, R16: software-pipelined persistent tiles. R10/R15 post-mortem: both
// land at 62.5 µs regardless of block count — the serial stage->vmcnt(0)
// drain->compute structure per block is the wall (per-block wall 7-9 µs vs
// ~1.1 µs issue work/SIMD; VALUBusy 45%). Fix: each block owns one MEMBER
// (branch,p) and a CHUNK of 5 j-tiles with a double-buffered LDS B tile.
// Per tile: issue STAGE(buf^1, t+1) right after the previous barrier, then
// compute tile t (MFMA+epilogue ~1.7K cycles), THEN barrier — the drain of
// stage(t+1) is hidden under tile t's compute. One barrier per tile.
// A-fragments live in REGISTERS for the whole block (avk[4][4], 64 VGPR) —
// no per-tile A/cnorm traffic. Register budget ~190-230 incl. 64-AGPR acc:
// __launch_bounds__(256,2) caps at 256 (R14 lesson: budget the accumulator).
// LDS 2x32KB -> 2 blocks/CU, 8 waves/CU. Grid: 64 groups x 16 members; all
// 16 members of a group share id%8 -> one XCD L2 for the chunk's 5 B tiles.
// Per-(jt,mm) math, reduction order, partials layout bit-identical to R10.
__global__ __launch_bounds__(256, 2) void main_k(const unsigned short* __restrict__ c_bf,
                                                 const unsigned short* __restrict__ ent_bf,
                                                 const float* __restrict__ cnorm,
                                                 const float* __restrict__ enorm,
                                                 const int* __restrict__ l1_flag,
                                                 const int* __restrict__ pos_h,
                                                 const int* __restrict__ neg_h,
                                                 const float* __restrict__ rpos,
                                                 const float* __restrict__ rneg,
                                                 const float* __restrict__ ent_f32,
                                                 float* __restrict__ partials) {
  __shared__ unsigned short smem[2][128 * 128];   // 64 KB: double-buffered B tile
  __shared__ float s4[2][4];                      // [buffer parity][wave]
  const int id = blockIdx.x;
  const int c8 = id & 7;
  const int q  = id >> 3;
  const int mm = q & 15;                          // member 0..15
  const int gg = q >> 4;                          // 0..7
  const int gp = c8 * 8 + gg;                     // group 0..63
  const int jtB = gp * CH;
  if (jtB >= NJT) return;                         // block-uniform, pre-barrier
  const int nt = (jtB + CH <= NJT) ? CH : (NJT - jtB);
  const int branch = mm & 1;
  const int i0 = (mm >> 1) * 128;
  const int tid = threadIdx.x, lane = tid & 63, wv = tid >> 6;
  const int wm = wv >> 1, wn = wv & 1;
  const int r15 = lane & 15, quad = lane >> 4;

  // async stage of one 128x128 B tile into buffer `par`, swizzle c'=c^(row&15)
#define STAGE(par_, j0_) do {                                                  \
    _Pragma("unroll")                                                          \
    for (int i_ = 0; i_ < 8; ++i_) {                                           \
      int g_  = i_ * 256 + tid;     /* LDS dst = uniform base + lane*16 */     \
      int r_  = g_ >> 4;                                                       \
      int c_  = (g_ & 15) ^ (r_ & 15);                                         \
      int jr_ = (j0_) + r_; if (jr_ >= N_ENT) jr_ = N_ENT - 1;                 \
      const unsigned short* src_ = ent_bf + (size_t)jr_ * DDIM + c_ * 8;       \
      __builtin_amdgcn_global_load_lds((const AS1 void*)src_,                  \
          (AS3 void*)(&smem[par_][g_ * 8]), 16, 0, 0);                         \
    }                                                                          \
  } while (0)

  STAGE(0, jtB * 128);                            // tile 0 DMA in flight

  // ---- A fragments -> registers, ALL kc (stay live for the whole block) ----
  const unsigned short* Abase = c_bf + ((size_t)(branch << 10) + i0) * DDIM;
  s16x8 avk[4][4];                                // [kc][tm], 64 VGPRs
  #pragma unroll
  for (int tm = 0; tm < 4; ++tm) {
    const unsigned short* ar = Abase + (size_t)(wm * 64 + tm * 16 + r15) * DDIM + quad * 8;
    #pragma unroll
    for (int kc = 0; kc < 4; ++kc)
      avk[kc][tm] = *reinterpret_cast<const s16x8*>(ar + kc * 32);
  }

  float cnv[16];                                  // fixed for the whole block
  #pragma unroll
  for (int tm = 0; tm < 4; ++tm)
    #pragma unroll
    for (int r = 0; r < 4; ++r)
      cnv[tm * 4 + r] = cnorm[(branch << 10) + i0 + wm * 64 + tm * 16 + quad * 4 + r];

  float en[4];                                    // tile-0 entity norms
  #pragma unroll
  for (int tn = 0; tn < 4; ++tn) {
    int jg = jtB * 128 + wn * 64 + tn * 16 + r15;
    en[tn] = enorm[jg < N_ENT ? jg : N_ENT - 1];
  }

  const int l1 = *l1_flag;
  const f32x4 zf = {0.f, 0.f, 0.f, 0.f};

  __syncthreads();   // drains vmcnt: tile-0 B staged; A/cnv/en landed

  #pragma unroll 1
  for (int t = 0; t < nt; ++t) {
    const int jt  = jtB + t;
    const int j0  = jt * 128;
    const int par = t & 1;
    const bool haveNext = (t + 1) < nt;           // block-uniform

    // issue next tile's DMA NOW — its drain is ~1.7K cycles away (post-compute)
    if (haveNext) STAGE(par ^ 1, j0 + 128);

    float enx[4];                                 // prefetch next tile's norms
    if (haveNext) {
      #pragma unroll
      for (int tn = 0; tn < 4; ++tn) {
        int jg = j0 + 128 + wn * 64 + tn * 16 + r15;
        enx[tn] = enorm[jg < N_ENT ? jg : N_ENT - 1];
      }
    }

    f32x4 acc[4][4];
    #pragma unroll
    for (int a = 0; a < 4; ++a)
      #pragma unroll
      for (int b = 0; b < 4; ++b) acc[a][b] = zf;

    #pragma unroll
    for (int kc = 0; kc < 4; ++kc) {
      s16x8 bv[4];
      #pragma unroll
      for (int tn = 0; tn < 4; ++tn) {
        int R  = wn * 64 + tn * 16 + r15;
        int cs = (kc * 4 + quad) ^ r15;
        bv[tn] = *reinterpret_cast<const s16x8*>(&smem[par][R * 128 + cs * 8]);
      }
      #pragma unroll
      for (int tm = 0; tm < 4; ++tm)
        #pragma unroll
        for (int tn = 0; tn < 4; ++tn)
          acc[tm][tn] = __builtin_amdgcn_mfma_f32_16x16x32_bf16(avk[kc][tm], bv[tn], acc[tm][tn], 0, 0, 0);
    }

    // ---- epilogue: add, fma, rsqrt, fmin, add (u-units), 4 accumulators ----
    const bool full = (j0 + 128) <= N_ENT;        // block-uniform per tile
    float ls0 = 0.f, ls1 = 0.f, ls2 = 0.f, ls3 = 0.f;
    if (!l1) {
      #pragma unroll
      for (int tm = 0; tm < 4; ++tm) {
        if (full) {
          #pragma unroll
          for (int tn = 0; tn < 4; ++tn) {
            float e0 = en[tn];
            float u0 = rsqrtf(fmaf(-2.f, acc[tm][tn][0], cnv[tm * 4 + 0] + e0));
            float u1 = rsqrtf(fmaf(-2.f, acc[tm][tn][1], cnv[tm * 4 + 1] + e0));
            float u2 = rsqrtf(fmaf(-2.f, acc[tm][tn][2], cnv[tm * 4 + 2] + e0));
            float u3 = rsqrtf(fmaf(-2.f, acc[tm][tn][3], cnv[tm * 4 + 3] + e0));
            ls0 += fminf(u0, U_CLAMP);            // <=0/NaN -> fmin clamps
            ls1 += fminf(u1, U_CLAMP);
            ls2 += fminf(u2, U_CLAMP);
            ls3 += fminf(u3, U_CLAMP);
          }
        } else {
          #pragma unroll
          for (int tn = 0; tn < 4; ++tn) {
            int jg = j0 + wn * 64 + tn * 16 + r15;
            if (jg < N_ENT) {
              float e0 = en[tn];
              ls0 += fminf(rsqrtf(fmaf(-2.f, acc[tm][tn][0], cnv[tm * 4 + 0] + e0)), U_CLAMP);
              ls1 += fminf(rsqrtf(fmaf(-2.f, acc[tm][tn][1], cnv[tm * 4 + 1] + e0)), U_CLAMP);
              ls2 += fminf(rsqrtf(fmaf(-2.f, acc[tm][tn][2], cnv[tm * 4 + 2] + e0)), U_CLAMP);
              ls3 += fminf(rsqrtf(fmaf(-2.f, acc[tm][tn][3], cnv[tm * 4 + 3] + e0)), U_CLAMP);
            }
          }
        }
      }
    } else {
      // L1 fallback (dead with this harness's inputs): recompute on the fly.
      const float* rs = branch ? rneg : rpos;
      const int*   hb = branch ? neg_h : pos_h;
      #pragma unroll 1
      for (int tm = 0; tm < 4; ++tm) {
        #pragma unroll 1
        for (int r = 0; r < 4; ++r) {
          int bi = i0 + wm * 64 + tm * 16 + quad * 4 + r;
          int hh = hb[bi];
          #pragma unroll 1
          for (int tn = 0; tn < 4; ++tn) {
            int jg = j0 + wn * 64 + tn * 16 + r15;
            if (jg < N_ENT) {
              const float* cp1 = ent_f32 + (size_t)hh * DDIM;
              const float* cp2 = rs + (size_t)bi * DDIM;
              const float* ep  = ent_f32 + (size_t)jg * DDIM;
              float man = 0.f;
              #pragma unroll 1
              for (int d = 0; d < DDIM; ++d) man += fabsf(cp1[d] + cp2[d] - ep[d]);
              float s = 100.f / fmaxf(man, 1e-12f);
              ls0 += 0.01f * fminf(s, S_CLAMP);   // same u-unit scale
            }
          }
        }
      }
    }
    float lsum = (ls0 + ls1) + (ls2 + ls3);

    #pragma unroll
    for (int m = 32; m; m >>= 1) lsum += __shfl_xor(lsum, m);
    if (lane == 0) s4[par][wv] = lsum;

    if (haveNext) {                               // rotate prefetched norms
      #pragma unroll
      for (int tn = 0; tn < 4; ++tn) en[tn] = enx[tn];
    }

    __syncthreads();   // drains stage(t+1) — issued ~1.7K cycles ago; s4 visible
    if (tid == 0)      // store overlaps next tile's compute; s4[par] safe until t+2
      partials[jt * 16 + mm] = s4[par][0] + s4[par][1] + s4[par][2] + s4[par][3];
  }
#undef STAGE
}

// Single-block deterministic finalize: 1024 threads; each sums ~5 partials
// (x 100/(B*N)) + its tpart element (x -1/(B*N)) in double, block-reduce,
// one plain store. No atomics -> no d_out memset node needed.
__global__ __launch_bounds__(1024) void finalize_k(const float* __restrict__ partials,
                                                   const float* __restrict__ tpart,
                                                   float* __restrict__ out) {
  const int tid = threadIdx.x, lane = tid & 63, wv = tid >> 6;
  const double inv = 1.0 / ((double)BSZ * (double)N_ENT);
  double v = 0.0;
  for (int i = tid; i < NPART; i += 1024) v += (double)partials[i] * (100.0 * inv);
  v += (double)tpart[tid] * (-inv);
  #pragma unroll
  for (int m = 32; m; m >>= 1) v += __shfl_xor(v, m);
  __shared__ double sd[16];
  if (lane == 0) sd[wv] = v;
  __syncthreads();
  if (wv == 0) {
    double t = (lane < 16) ? sd[lane] : 0.0;
    #pragma unroll
    for (int m = 8; m; m >>= 1) t += __shfl_xor(t, m);
    if (lane == 0) out[0] = (float)t;
  }
}

extern "C" void kernel_launch(void* const* d_in, const int* in_sizes, int n_in,
                              void* d_out, int out_size, void* d_ws, size_t ws_size,
                              hipStream_t stream) {
  const int*   pos_h = (const int*)d_in[0];
  const int*   pos_t = (const int*)d_in[1];
  const int*   neg_h = (const int*)d_in[2];
  // d_in[3] = neg_t_batch (unused by reference)
  const float* rpos  = (const float*)d_in[4];
  const float* rneg  = (const float*)d_in[5];
  const float* ent   = (const float*)d_in[6];
  const int*   l1    = (const int*)d_in[7];

  char* ws = (char*)d_ws;
  float*          partials = (float*)(ws + OFF_PART);
  float*          tpart    = (float*)(ws + OFF_TPART);
  float*          enorm    = (float*)(ws + OFF_ENORM);
  float*          cnorm    = (float*)(ws + OFF_CNORM);
  unsigned short* c_bf     = (unsigned short*)(ws + OFF_CBF);
  unsigned short* ent_bf   = (unsigned short*)(ws + OFF_EBF);

  prep_k<<<5256, 256, 0, stream>>>(ent, pos_h, pos_t, neg_h, rpos, rneg, l1,
                                   ent_bf, enorm, c_bf, cnorm, tpart);

  main_k<<<NGRID, 256, 0, stream>>>(c_bf, ent_bf, cnorm, enorm, l1,
                                    pos_h, neg_h, rpos, rneg, ent, partials);

  finalize_k<<<1, 1024, 0, stream>>>(partials, tpart, (float*)d_out);
}